// Round 1
// baseline (869.876 us; speedup 1.0000x reference)
//
#include <hip/hip_runtime.h>

// out = conv2d(poly(img), W, stride=1, pad=1) / 27
// poly(v) = P01 + P11*v + P21*v^2 ; identity-kernel branch is exactly zero.
// 1/27 folded into poly coefficients (conv is linear in the input).
static constexpr float A0 = -0.000287f / 27.0f;
static constexpr float A1 =  0.266f    / 27.0f;
static constexpr float A2 = -0.1097f   / 27.0f;

#define NN 16
#define CI 64
#define HH 128
#define WW 128
#define OO 64
#define CC 8   // c-chunk staged in LDS per iteration

// Repack weights [O][C][3][3] -> [C][ky][kx][O] so conv-kernel staging is coalesced.
__global__ void repack_w(const float* __restrict__ w, float* __restrict__ wr) {
    int idx = blockIdx.x * 256 + threadIdx.x;
    if (idx >= OO * CI * 9) return;
    int o = idx & 63;
    int rest = idx >> 6;            // c*9 + ky*3 + kx
    int kx = rest % 3;
    int t = rest / 3;
    int ky = t % 3;
    int c = t / 3;
    wr[idx] = w[((o * CI + c) * 3 + ky) * 3 + kx];
}

// One block per (n, y): computes out[n, 0..63, y, 0..127].
// Thread layout: og = tid>>4 (o-quad 0..15), xg = tid&15 (x-octet 0..15).
__global__ __launch_bounds__(256) void conv_poly(const float* __restrict__ img,
                                                 const float* __restrict__ wr,
                                                 float* __restrict__ out) {
    __shared__ float ilds[CC * 3 * 132];   // [c][r][132] rows of poly(img), pad stride 132
    __shared__ float wlds[CC * 576];       // [c][ky][kx][64]

    const int tid = threadIdx.x;
    const int b = blockIdx.x;
    const int y = b & 127;
    const int n = b >> 7;
    const int og = tid >> 4;
    const int xg = tid & 15;
    const int x0 = xg * 8;
    const int o0 = og * 4;

    float acc[4][8];
    #pragma unroll
    for (int a = 0; a < 4; ++a)
        #pragma unroll
        for (int j = 0; j < 8; ++j) acc[a][j] = 0.0f;

    for (int cc = 0; cc < CI / CC; ++cc) {
        const int c0 = cc * CC;
        __syncthreads();   // protect previous iteration's LDS reads

        // Stage poly(img) rows y-1..y+1 for channels c0..c0+CC-1 (boundary -> 0).
        for (int i = tid; i < CC * 3 * 130; i += 256) {
            int c = i / 390;                // 390 = 3*130
            int rem = i - c * 390;
            int r = rem / 130;
            int xcol = rem - r * 130;       // 0..129
            int xi = xcol - 1;              // -1..128
            int yi = y + r - 1;
            float v = 0.0f;
            if ((unsigned)yi < 128u && (unsigned)xi < 128u) {
                float t = img[((n * CI + c0 + c) * HH + yi) * WW + xi];
                v = A0 + t * (A1 + A2 * t);
            }
            ilds[c * 396 + r * 132 + xcol] = v;
        }
        // Stage chunk weights (already in [c][ky][kx][o] order), float4 copy.
        {
            const float4* src4 = (const float4*)(wr + c0 * 576);
            float4* dst4 = (float4*)wlds;
            for (int i = tid; i < CC * 144; i += 256) dst4[i] = src4[i];
        }
        __syncthreads();

        // Accumulate: per (c,ky): 10 input vals + 3 o-quad weight vectors -> 96 FMAs.
        #pragma unroll
        for (int c = 0; c < CC; ++c) {
            #pragma unroll
            for (int ky = 0; ky < 3; ++ky) {
                const float* row = &ilds[c * 396 + ky * 132 + x0];
                float4 va = *(const float4*)row;
                float4 vb = *(const float4*)(row + 4);
                float2 vc = *(const float2*)(row + 8);
                float vals[10] = {va.x, va.y, va.z, va.w,
                                  vb.x, vb.y, vb.z, vb.w,
                                  vc.x, vc.y};
                const float4* wbase = (const float4*)&wlds[(c * 9 + ky * 3) * 64];
                float4 w0 = wbase[og];
                float4 w1 = wbase[16 + og];
                float4 w2 = wbase[32 + og];
                #pragma unroll
                for (int j = 0; j < 8; ++j) {
                    float s0 = vals[j], s1 = vals[j + 1], s2 = vals[j + 2];
                    acc[0][j] += s0 * w0.x + s1 * w1.x + s2 * w2.x;
                    acc[1][j] += s0 * w0.y + s1 * w1.y + s2 * w2.y;
                    acc[2][j] += s0 * w0.z + s1 * w1.z + s2 * w2.z;
                    acc[3][j] += s0 * w0.w + s1 * w1.w + s2 * w2.w;
                }
            }
        }
    }

    // Store: 4 o-rows x 8 consecutive x, two float4s each (16B-aligned).
    #pragma unroll
    for (int oo = 0; oo < 4; ++oo) {
        float* p = out + (((n * OO + o0 + oo) * HH + y) * WW + x0);
        *(float4*)p       = make_float4(acc[oo][0], acc[oo][1], acc[oo][2], acc[oo][3]);
        *((float4*)p + 1) = make_float4(acc[oo][4], acc[oo][5], acc[oo][6], acc[oo][7]);
    }
}

extern "C" void kernel_launch(void* const* d_in, const int* in_sizes, int n_in,
                              void* d_out, int out_size, void* d_ws, size_t ws_size,
                              hipStream_t stream) {
    const float* img = (const float*)d_in[0];
    const float* w   = (const float*)d_in[1];
    // d_in[2] (identity_kernel) unused: its branch convolves exact zeros.
    float* out = (float*)d_out;
    float* wr  = (float*)d_ws;   // 36864 floats = 144 KB repacked weights

    repack_w<<<(OO * CI * 9 + 255) / 256, 256, 0, stream>>>(w, wr);
    conv_poly<<<NN * HH, 256, 0, stream>>>(img, wr, out);
}

// Round 2
// 138.207 us; speedup vs baseline: 6.2940x; 6.2940x over previous
//
#include <hip/hip_runtime.h>

// out = conv2d(poly(img), W, stride=1, pad=1) / 27, poly(v) = A0 + A1*v + A2*v^2
// (identity-kernel branch contributes exactly zero; 1/27 folded into poly).
// Implemented as implicit GEMM on bf16 MFMA: A = weights (M=o), B = poly(img)
// (N = spatial x), K = (ky,kx,c) = 576, mfma_f32_32x32x16_bf16.

typedef __bf16 bf16;
typedef __attribute__((ext_vector_type(8))) __bf16 bf16x8;
typedef __attribute__((ext_vector_type(16))) float f32x16;

static constexpr float A0 = -0.000287f / 27.0f;
static constexpr float A1 =  0.266f    / 27.0f;
static constexpr float A2 = -0.1097f   / 27.0f;

#define NN 16
#define CI 64
#define HH 128
#define WW 128
#define OO 64

// Repack weights [O][C][3][3] fp32 -> [slice=ky*3+kx][cc8=c/8][o][cj=c%8] bf16.
// A-fragment load for (slice, k-chunk, o-row) is then a single coalesced 16B read.
__global__ void repack_w(const float* __restrict__ w, bf16* __restrict__ wrb) {
    int idx = blockIdx.x * 256 + threadIdx.x;        // 9*8*64*8 = 36864
    if (idx >= 9 * 8 * 64 * 8) return;
    int cj    = idx & 7;
    int o     = (idx >> 3) & 63;
    int cc8   = (idx >> 9) & 7;
    int slice = idx >> 12;
    int ky = slice / 3, kx = slice - ky * 3;
    int c = cc8 * 8 + cj;
    wrb[idx] = (bf16)w[((o * CI + c) * 3 + ky) * 3 + kx];
}

// One block per (n, y-pair). Block = 256 threads = 4 waves.
// Wave w: y_local = w>>1, x-half = (w&1)*64; computes 2 o-tiles x 2 x-tiles of 32x32.
__global__ __launch_bounds__(256) void conv_mfma(const float* __restrict__ img,
                                                 const bf16* __restrict__ wrb,
                                                 float* __restrict__ out) {
    // poly(img) staged for 4 input rows: [r=0..3][cc8=0..7][x'=0..129][8c] bf16.
    // Both ds_write_b128 (staging) and ds_read_b128 (B-frags) are lane-contiguous
    // 16B => conflict-free.
    __shared__ __align__(16) bf16 ilds[4 * 8 * 130 * 8];   // 66560 B

    const int tid = threadIdx.x;
    const int b   = blockIdx.x;
    const int y0  = (b & 63) * 2;
    const int n   = b >> 6;

    // ---- Stage poly(img) -> LDS (once per block; no K-loop barriers) ----
    for (int t = tid; t < 4 * 8 * 130; t += 256) {
        int r   = t / (8 * 130);
        int rem = t - r * (8 * 130);
        int cc8 = rem / 130;
        int xp  = rem - cc8 * 130;      // x' in [0,130)
        int yi  = y0 - 1 + r;
        int xi  = xp - 1;
        bf16x8 pk;
        if ((unsigned)yi < 128u && (unsigned)xi < 128u) {
            const float* p = img + ((n * CI + cc8 * 8) * HH + yi) * WW + xi;
            #pragma unroll
            for (int j = 0; j < 8; ++j) {
                float v = p[j * HH * WW];            // coalesced across lanes (x)
                pk[j] = (bf16)(A0 + v * (A1 + A2 * v));
            }
        } else {
            #pragma unroll
            for (int j = 0; j < 8; ++j) pk[j] = (bf16)0.0f;
        }
        *(bf16x8*)&ilds[t * 8] = pk;
    }
    __syncthreads();

    const int wv   = tid >> 6;
    const int lane = tid & 63;
    const int lm   = lane & 31;      // A: o-row / B: x-col / C: col
    const int half = lane >> 5;      // k-half selector
    const int yl   = wv >> 1;        // which of the 2 output rows
    const int Xh   = (wv & 1) * 64;  // x-half of this wave

    f32x16 acc[2][2];
    #pragma unroll
    for (int i = 0; i < 2; ++i)
        #pragma unroll
        for (int j = 0; j < 2; ++j)
            #pragma unroll
            for (int k = 0; k < 16; ++k) acc[i][j][k] = 0.0f;

    const bf16x8* wfr = (const bf16x8*)wrb;
    const bf16x8* ifr = (const bf16x8*)ilds;

    for (int ky = 0; ky < 3; ++ky) {
        const int r = yl + ky;
        #pragma unroll
        for (int kx = 0; kx < 3; ++kx) {
            const int slice = ky * 3 + kx;
            #pragma unroll
            for (int cs = 0; cs < 8; cs += 2) {      // 16 c per k-step
                const int cc = cs + half;
                // A-frags (weights) from global: coalesced 16B/lane, L1/L2-hot.
                bf16x8 a0 = wfr[(slice * 8 + cc) * 64 + lm];
                bf16x8 a1 = wfr[(slice * 8 + cc) * 64 + 32 + lm];
                // B-frags (image) from LDS: conflict-free 16B/lane.
                const int ibase = (r * 8 + cc) * 130 + Xh + lm + kx;
                bf16x8 b0 = ifr[ibase];
                bf16x8 b1 = ifr[ibase + 32];
                acc[0][0] = __builtin_amdgcn_mfma_f32_32x32x16_bf16(a0, b0, acc[0][0], 0, 0, 0);
                acc[0][1] = __builtin_amdgcn_mfma_f32_32x32x16_bf16(a0, b1, acc[0][1], 0, 0, 0);
                acc[1][0] = __builtin_amdgcn_mfma_f32_32x32x16_bf16(a1, b0, acc[1][0], 0, 0, 0);
                acc[1][1] = __builtin_amdgcn_mfma_f32_32x32x16_bf16(a1, b1, acc[1][1], 0, 0, 0);
            }
        }
    }

    // ---- Epilogue: C/D layout col=lane&31 (x), row=(reg&3)+8*(reg>>2)+4*half (o).
    // Stores are coalesced across lanes (consecutive x).
    const int y = y0 + yl;
    #pragma unroll
    for (int ot = 0; ot < 2; ++ot) {
        #pragma unroll
        for (int xt = 0; xt < 2; ++xt) {
            const int x = Xh + xt * 32 + lm;
            #pragma unroll
            for (int rg = 0; rg < 16; ++rg) {
                const int o = ot * 32 + (rg & 3) + 8 * (rg >> 2) + 4 * half;
                out[((n * OO + o) * HH + y) * WW + x] = acc[ot][xt][rg];
            }
        }
    }
}

extern "C" void kernel_launch(void* const* d_in, const int* in_sizes, int n_in,
                              void* d_out, int out_size, void* d_ws, size_t ws_size,
                              hipStream_t stream) {
    const float* img = (const float*)d_in[0];
    const float* w   = (const float*)d_in[1];
    // d_in[2] (identity_kernel) unused: its branch convolves exact zeros.
    float* out = (float*)d_out;
    bf16* wrb  = (bf16*)d_ws;    // 36864 bf16 = 73728 B repacked weights

    repack_w<<<(9 * 8 * 64 * 8 + 255) / 256, 256, 0, stream>>>(w, wrb);
    conv_mfma<<<NN * (HH / 2), 256, 0, stream>>>(img, wrb, out);
}

// Round 3
// 132.474 us; speedup vs baseline: 6.5664x; 1.0433x over previous
//
#include <hip/hip_runtime.h>

// out = conv2d(poly(img), W, stride=1, pad=1) / 27, poly(v) = A0 + A1*v + A2*v^2
// (identity-kernel branch contributes exactly zero; 1/27 folded into poly).
// Implicit GEMM on bf16 MFMA: A = weights (M=o), B = poly(img) (N = spatial x),
// K = (ky,kx,c) = 576, mfma_f32_32x32x16_bf16.
//
// R3 structure: block = (n, 4 output rows) = 512 blocks (fully co-resident at
// 2 blocks/CU), 512 threads = 8 waves. K-loop over 4 channel-chunks (16 c),
// double-buffered 25 KB LDS stages so stage(k+1) overlaps compute(k).

typedef __bf16 bf16;
typedef __attribute__((ext_vector_type(8))) __bf16 bf16x8;
typedef __attribute__((ext_vector_type(16))) float f32x16;

static constexpr float A0 = -0.000287f / 27.0f;
static constexpr float A1 =  0.266f    / 27.0f;
static constexpr float A2 = -0.1097f   / 27.0f;

#define NN 16
#define CI 64
#define HH 128
#define WW 128
#define OO 64

// Repack weights [O][C][3][3] fp32 -> [slice=ky*3+kx][cc8=c/8][o][cj=c%8] bf16.
__global__ void repack_w(const float* __restrict__ w, bf16* __restrict__ wrb) {
    int idx = blockIdx.x * 256 + threadIdx.x;        // 9*8*64*8 = 36864
    if (idx >= 9 * 8 * 64 * 8) return;
    int cj    = idx & 7;
    int o     = (idx >> 3) & 63;
    int cc8   = (idx >> 9) & 7;
    int slice = idx >> 12;
    int ky = slice / 3, kx = slice - ky * 3;
    int c = cc8 * 8 + cj;
    wrb[idx] = (bf16)w[((o * CI + c) * 3 + ky) * 3 + kx];
}

// Wave wv: yl = wv>>1 (output row 0..3), Xh = (wv&1)*64 (x-half).
// Each wave: 2 o-tiles x 2 x-tiles of 32x32 = 64 acc VGPRs.
__global__ __launch_bounds__(512, 4) void conv_mfma(const float* __restrict__ img,
                                                    const bf16* __restrict__ wrb,
                                                    float* __restrict__ out) {
    // Per chunk: 6 input rows x 2 cc8 (16 ch) x 130 x' x 8 cj bf16 = 24960 B.
    // [r][ccl][x'][cj] -> both ds_write_b128 and ds_read_b128 lane-contiguous.
    __shared__ __align__(16) bf16 ilds[2][6 * 2 * 130 * 8];

    const int tid = threadIdx.x;
    const int b   = blockIdx.x;
    const int y0  = (b & 31) * 4;
    const int n   = b >> 5;

    const int wv   = tid >> 6;
    const int lane = tid & 63;
    const int lm   = lane & 31;      // A: o-row / B: x-col / C: col
    const int half = lane >> 5;      // k-half selector (which cc8 of the pair)
    const int yl   = wv >> 1;
    const int Xh   = (wv & 1) * 64;

    auto stage = [&](int chunk, int buf) {
        const int cbase = chunk * 16;
        for (int t = tid; t < 6 * 2 * 130; t += 512) {
            int r   = t / 260;
            int rem = t - r * 260;
            int ccl = rem / 130;
            int xp  = rem - ccl * 130;     // x' in [0,130)
            int yi  = y0 - 1 + r;
            int xi  = xp - 1;
            bf16x8 pk;
            if ((unsigned)yi < 128u && (unsigned)xi < 128u) {
                const float* p = img + ((n * CI + cbase + ccl * 8) * HH + yi) * WW + xi;
                #pragma unroll
                for (int j = 0; j < 8; ++j) {
                    float v = p[j * HH * WW];          // coalesced across lanes (x)
                    pk[j] = (bf16)(A0 + v * (A1 + A2 * v));
                }
            } else {
                #pragma unroll
                for (int j = 0; j < 8; ++j) pk[j] = (bf16)0.0f;   // conv zero-pad
            }
            *(bf16x8*)&ilds[buf][((r * 2 + ccl) * 130 + xp) * 8] = pk;
        }
    };

    f32x16 acc[2][2];
    #pragma unroll
    for (int i = 0; i < 2; ++i)
        #pragma unroll
        for (int j = 0; j < 2; ++j)
            #pragma unroll
            for (int k = 0; k < 16; ++k) acc[i][j][k] = 0.0f;

    const bf16x8* wfr = (const bf16x8*)wrb;

    stage(0, 0);

    for (int chunk = 0; chunk < 4; ++chunk) {
        __syncthreads();                       // stage(chunk) complete; buf chunk&1 free of readers
        if (chunk < 3) stage(chunk + 1, (chunk + 1) & 1);   // overlap with compute below
        const bf16x8* ifr = (const bf16x8*)ilds[chunk & 1];
        const int cc8g = chunk * 2 + half;     // global cc8 this lane-half contracts
        #pragma unroll
        for (int ky = 0; ky < 3; ++ky) {
            const int r = yl + ky;
            #pragma unroll
            for (int kx = 0; kx < 3; ++kx) {
                const int slice = ky * 3 + kx;
                // A-frags (weights) from global: 16B/lane coalesced, 18 KB/chunk -> L1-hot.
                bf16x8 a0 = wfr[(slice * 8 + cc8g) * 64 + lm];
                bf16x8 a1 = wfr[(slice * 8 + cc8g) * 64 + 32 + lm];
                // B-frags (image) from LDS: conflict-free ds_read_b128.
                const int ib = (r * 2 + half) * 130 + Xh + lm + kx;
                bf16x8 b0 = ifr[ib];
                bf16x8 b1 = ifr[ib + 32];
                acc[0][0] = __builtin_amdgcn_mfma_f32_32x32x16_bf16(a0, b0, acc[0][0], 0, 0, 0);
                acc[0][1] = __builtin_amdgcn_mfma_f32_32x32x16_bf16(a0, b1, acc[0][1], 0, 0, 0);
                acc[1][0] = __builtin_amdgcn_mfma_f32_32x32x16_bf16(a1, b0, acc[1][0], 0, 0, 0);
                acc[1][1] = __builtin_amdgcn_mfma_f32_32x32x16_bf16(a1, b1, acc[1][1], 0, 0, 0);
            }
        }
    }

    // Epilogue: C/D layout col=lane&31 (x), row=(reg&3)+8*(reg>>2)+4*half (o).
    const int y = y0 + yl;
    #pragma unroll
    for (int ot = 0; ot < 2; ++ot) {
        #pragma unroll
        for (int xt = 0; xt < 2; ++xt) {
            const int x = Xh + xt * 32 + lm;
            #pragma unroll
            for (int rg = 0; rg < 16; ++rg) {
                const int o = ot * 32 + (rg & 3) + 8 * (rg >> 2) + 4 * half;
                out[((n * OO + o) * HH + y) * WW + x] = acc[ot][xt][rg];
            }
        }
    }
}

extern "C" void kernel_launch(void* const* d_in, const int* in_sizes, int n_in,
                              void* d_out, int out_size, void* d_ws, size_t ws_size,
                              hipStream_t stream) {
    const float* img = (const float*)d_in[0];
    const float* w   = (const float*)d_in[1];
    // d_in[2] (identity_kernel) unused: its branch convolves exact zeros.
    float* out = (float*)d_out;
    bf16* wrb  = (bf16*)d_ws;    // 36864 bf16 = 73728 B repacked weights

    repack_w<<<(9 * 8 * 64 * 8 + 255) / 256, 256, 0, stream>>>(w, wrb);
    conv_mfma<<<NN * (HH / 4), 512, 0, stream>>>(img, wrb, out);
}

// Round 4
// 129.607 us; speedup vs baseline: 6.7117x; 1.0221x over previous
//
#include <hip/hip_runtime.h>

// out = conv2d(poly(img), W, stride=1, pad=1) / 27, poly(v) = A0 + A1*v + A2*v^2
// (identity-kernel branch contributes exactly zero; 1/27 folded into poly).
// Implicit GEMM on bf16 MFMA: A = weights (M=o), B = poly(img) (N = spatial x),
// K = (ky,kx,c) = 576, mfma_f32_32x32x16_bf16.
//
// R4: R3 skeleton (512 blocks = (n, 4 output rows), 512 thr, double-buffered
// 16-ch chunks) + burst-size fixes: float2 staging loads, and an LDS-transpose
// epilogue so all global stores are dwordx4 (1 KB/wave-instr, contiguous).

typedef __bf16 bf16;
typedef __attribute__((ext_vector_type(8))) __bf16 bf16x8;
typedef __attribute__((ext_vector_type(16))) float f32x16;

static constexpr float A0 = -0.000287f / 27.0f;
static constexpr float A1 =  0.266f    / 27.0f;
static constexpr float A2 = -0.1097f   / 27.0f;

#define NN 16
#define CI 64
#define HH 128
#define WW 128
#define OO 64

// Repack weights [O][C][3][3] fp32 -> [slice=ky*3+kx][cc8=c/8][o][cj=c%8] bf16.
__global__ void repack_w(const float* __restrict__ w, bf16* __restrict__ wrb) {
    int idx = blockIdx.x * 256 + threadIdx.x;        // 9*8*64*8 = 36864
    if (idx >= 9 * 8 * 64 * 8) return;
    int cj    = idx & 7;
    int o     = (idx >> 3) & 63;
    int cc8   = (idx >> 9) & 7;
    int slice = idx >> 12;
    int ky = slice / 3, kx = slice - ky * 3;
    int c = cc8 * 8 + cj;
    wrb[idx] = (bf16)w[((o * CI + c) * 3 + ky) * 3 + kx];
}

__global__ __launch_bounds__(512, 4) void conv_mfma(const float* __restrict__ img,
                                                    const bf16* __restrict__ wrb,
                                                    float* __restrict__ out) {
    // Staging: [buf 2][r 6][ccl 2][xp 130][cj 8] bf16 = 2 x 24960 B.
    // Epilogue reuses the same space as [o16 16][y 4][x 128] f32 = 32768 B.
    __shared__ __align__(16) char smem[49920];
    bf16*  ilds = (bf16*)smem;
    float* elds = (float*)smem;

    const int tid = threadIdx.x;
    const int b   = blockIdx.x;
    const int y0  = (b & 31) * 4;
    const int n   = b >> 5;

    const int wv   = tid >> 6;
    const int lane = tid & 63;
    const int lm   = lane & 31;      // A: o-row / B: x-col / C: col
    const int half = lane >> 5;      // k-half selector (which cc8 of the pair)
    const int yl   = wv >> 1;
    const int Xh   = (wv & 1) * 64;

    // Stage poly(img) chunk (16 channels) into LDS buffer buf.
    // Thread t -> (r, ccl, xh): xh<64 loads aligned float2 (x = 2xh, 2xh+1),
    // writing xp = 2xh+1, 2xh+2; xh==64 zero-fills the two halo columns.
    auto stage = [&](int chunk, int buf) {
        const int cbase = chunk * 16;
        bf16* dst = ilds + buf * 12480;
        for (int t = tid; t < 780; t += 512) {     // 6r * 2ccl * 65
            int r   = t / 130;
            int rem = t - r * 130;
            int ccl = rem / 65;
            int xh  = rem - ccl * 65;
            int yi  = y0 - 1 + r;
            bf16* rowp = dst + (r * 2 + ccl) * (130 * 8);
            if (xh < 64) {
                bf16x8 pk0, pk1;
                if ((unsigned)yi < 128u) {
                    const float* p = img + ((n * CI + cbase + ccl * 8) * HH + yi) * WW + 2 * xh;
                    #pragma unroll
                    for (int j = 0; j < 8; ++j) {
                        float2 v = *(const float2*)(p + j * HH * WW);   // 8B aligned
                        pk0[j] = (bf16)(A0 + v.x * (A1 + A2 * v.x));
                        pk1[j] = (bf16)(A0 + v.y * (A1 + A2 * v.y));
                    }
                } else {
                    #pragma unroll
                    for (int j = 0; j < 8; ++j) { pk0[j] = (bf16)0.0f; pk1[j] = (bf16)0.0f; }
                }
                *(bf16x8*)(rowp + (2 * xh + 1) * 8) = pk0;
                *(bf16x8*)(rowp + (2 * xh + 2) * 8) = pk1;
            } else {
                bf16x8 z;
                #pragma unroll
                for (int j = 0; j < 8; ++j) z[j] = (bf16)0.0f;
                *(bf16x8*)(rowp + 0) = z;            // xp=0   (xi=-1, conv pad)
                *(bf16x8*)(rowp + 129 * 8) = z;      // xp=129 (xi=128, conv pad)
            }
        }
    };

    f32x16 acc[2][2];
    #pragma unroll
    for (int i = 0; i < 2; ++i)
        #pragma unroll
        for (int j = 0; j < 2; ++j)
            #pragma unroll
            for (int k = 0; k < 16; ++k) acc[i][j][k] = 0.0f;

    const bf16x8* wfr = (const bf16x8*)wrb;

    stage(0, 0);

    for (int chunk = 0; chunk < 4; ++chunk) {
        __syncthreads();
        if (chunk < 3) stage(chunk + 1, (chunk + 1) & 1);
        const bf16x8* ifr = (const bf16x8*)(ilds + (chunk & 1) * 12480);
        const int cc8g = chunk * 2 + half;
        #pragma unroll
        for (int ky = 0; ky < 3; ++ky) {
            const int r = yl + ky;
            #pragma unroll
            for (int kx = 0; kx < 3; ++kx) {
                const int slice = ky * 3 + kx;
                bf16x8 a0 = wfr[(slice * 8 + cc8g) * 64 + lm];        // weights, L1-hot
                bf16x8 a1 = wfr[(slice * 8 + cc8g) * 64 + 32 + lm];
                const int ib = (r * 2 + half) * 130 + Xh + lm + kx;   // conflict-free b128
                bf16x8 b0 = ifr[ib];
                bf16x8 b1 = ifr[ib + 32];
                acc[0][0] = __builtin_amdgcn_mfma_f32_32x32x16_bf16(a0, b0, acc[0][0], 0, 0, 0);
                acc[0][1] = __builtin_amdgcn_mfma_f32_32x32x16_bf16(a0, b1, acc[0][1], 0, 0, 0);
                acc[1][0] = __builtin_amdgcn_mfma_f32_32x32x16_bf16(a1, b0, acc[1][0], 0, 0, 0);
                acc[1][1] = __builtin_amdgcn_mfma_f32_32x32x16_bf16(a1, b1, acc[1][1], 0, 0, 0);
            }
        }
    }

    // ---- Epilogue: 4 passes of 16 o-rows through LDS, stores as dwordx4. ----
    // C/D layout: col = lane&31 (x), row-in-32 = (rg&3) + 8*(rg>>2) + 4*half (o).
    #pragma unroll
    for (int p = 0; p < 4; ++p) {
        const int ot  = p >> 1;
        const int sub = p & 1;             // selects rg>>2 in {2sub, 2sub+1}
        __syncthreads();                   // LDS free (staging/previous pass read done)
        #pragma unroll
        for (int xt = 0; xt < 2; ++xt) {
            const int x = Xh + xt * 32 + lm;
            #pragma unroll
            for (int q = 0; q < 2; ++q) {
                #pragma unroll
                for (int rb = 0; rb < 4; ++rb) {
                    const int rg  = (sub * 2 + q) * 4 + rb;
                    const int o16 = rb + 8 * q + 4 * half;           // o-local in [0,16)
                    elds[(o16 * 4 + yl) * 128 + x] = acc[ot][xt][rg];
                }
            }
        }
        __syncthreads();
        // 2048 float4s: idx -> (o16 = idx>>7, yy = (idx>>5)&3, x4 = idx&31).
        #pragma unroll
        for (int j = 0; j < 4; ++j) {
            const int idx = tid + j * 512;
            const int x4  = idx & 31;
            const int yy  = (idx >> 5) & 3;
            const int o16 = idx >> 7;
            float4 v = ((const float4*)elds)[idx];                    // lane-contiguous
            float* dstp = out + ((n * OO + p * 16 + o16) * HH + (y0 + yy)) * WW + x4 * 4;
            *(float4*)dstp = v;                                       // 1 KB/wave-instr
        }
    }
}

extern "C" void kernel_launch(void* const* d_in, const int* in_sizes, int n_in,
                              void* d_out, int out_size, void* d_ws, size_t ws_size,
                              hipStream_t stream) {
    const float* img = (const float*)d_in[0];
    const float* w   = (const float*)d_in[1];
    // d_in[2] (identity_kernel) unused: its branch convolves exact zeros.
    float* out = (float*)d_out;
    bf16* wrb  = (bf16*)d_ws;    // 36864 bf16 = 73728 B repacked weights

    repack_w<<<(9 * 8 * 64 * 8 + 255) / 256, 256, 0, stream>>>(w, wrb);
    conv_mfma<<<NN * (HH / 4), 512, 0, stream>>>(img, wrb, out);
}